// Round 2
// baseline (375.852 us; speedup 1.0000x reference)
//
#include <hip/hip_runtime.h>

// C51 categorical projection — round 5: wave-private DMA pipeline (R4 rerun, hardened).
//   R3 diagnosis: 2.2 TB/s (28% peak), VALU 27%, occupancy 51% -> nothing
//   saturated = latency/duty-cycle bound. Phase-serial blocks + __syncthreads
//   vmcnt(0) drains kept reads in flight only ~10% of the time.
//   R4 bench: container failed (no counters). Audit found no fault candidate;
//   treating as infra flake. R5 = same design, hardened:
//     - tile loop fully unrolled (prefetch predicate is compile-time)
//     - sched_barrier(0) after each counted wait (rule-18 hoist protection)
//   Design:
//     - 1 wave/block, 64-row f32 tile, double-buffered (2x13056 B LDS).
//       Tile is wave-private -> ZERO barriers.
//     - global_load_lds stages the tile (12x16B + 3x4B = 13056 B exact):
//       no VGPR round-trip, no bf16 pack; DMA overlaps compute on other buffer.
//     - 4 tiles/block, counted s_waitcnt vmcnt(13) (never 0): batch = 17 VMEM
//       ops (r, m, 15 DMA). At each tile top outstanding <= [cur batch rem 13]
//       [prev stores 13][next batch 17]; in-order retirement (m135) => draining
//       to 13 completes exactly the current batch.
//     - f32 [64][51] LDS: stride 51 dwords, gcd(51,32)=1 -> 2-way max = free.
//       Writeout ds_read_b128 -> global_store_dwordx4 (12 full + 48-lane tail).
//     - supports[] read at uniform addresses -> s_load/SGPR (R3: SGPR=112),
//       so it does NOT pollute the vmcnt budget.
//   Occupancy 6 waves/CU by design; ~26 KB reads in flight/CU >> ~9 KB
//   Little's-law need at 900cy -> BW-paced. Target 75-95 us (roofline ~69).

#define ATOMS   51
#define ROWS    64                    // threads per block == rows per tile (1 wave)
#define TILE_F  (ROWS * ATOMS)        // 3264 floats = 13056 bytes
#define TPB     4                     // tiles per block

#define WAIT_VM13()  asm volatile("s_waitcnt vmcnt(13)" ::: "memory")
#define WAIT_LGKM0() asm volatile("s_waitcnt lgkmcnt(0)" ::: "memory")
#define SCHED_FENCE() __builtin_amdgcn_sched_barrier(0)

#define GLOAD_LDS16(g, l)                                                       \
  __builtin_amdgcn_global_load_lds(                                             \
      (const __attribute__((address_space(1))) void*)(g),                       \
      (__attribute__((address_space(3))) void*)(l), 16, 0, 0)
#define GLOAD_LDS4(g, l)                                                        \
  __builtin_amdgcn_global_load_lds(                                             \
      (const __attribute__((address_space(1))) void*)(g),                       \
      (__attribute__((address_space(3))) void*)(l), 4, 0, 0)

// Issue one tile's load batch: reward + mask + 15 DMA insts (17 VMEM ops).
// 12 x (64 lanes * 16 B) = 12288 B, then 3 x (64 lanes * 4 B) = 768 B -> 13056 B.
#define ISSUE_TILE(TT, S, RREG, MREG) do {                                      \
    const int rowg_ = (TT) * ROWS + lane;                                       \
    RREG = reward[rowg_];                                                       \
    MREG = (float)mask[rowg_];                                                  \
    const float* gsrc_ = dist + (size_t)(TT) * TILE_F;                          \
    _Pragma("unroll")                                                           \
    for (int k = 0; k < 12; ++k)                                                \
      GLOAD_LDS16(gsrc_ + k * 256 + lane * 4, &smem[S][k * 256]);               \
    _Pragma("unroll")                                                           \
    for (int k = 0; k < 3; ++k)                                                 \
      GLOAD_LDS4(gsrc_ + 3072 + k * 64 + lane, &smem[S][3072 + k * 64]);        \
  } while (0)

// One pipeline stage: wait own tile, compute in place, write out, prefetch t+2.
#define BODY(TIDX, S, RREG, MREG, DO_ISSUE) do {                                \
    const int tt_ = tile0 + (TIDX);                                             \
    WAIT_VM13();                      /* drains batch(t) + prev stores */       \
    SCHED_FENCE();                    /* keep ds_reads below the wait */        \
    float* row = &smem[S][lane * ATOMS];                                        \
    float p[ATOMS];                                                             \
    _Pragma("unroll")                                                           \
    for (int j = 0; j < ATOMS; ++j) p[j] = row[j];                              \
    _Pragma("unroll")                                                           \
    for (int j = 0; j < ATOMS; ++j) row[j] = 0.0f;                              \
    const float r_  = RREG;                                                     \
    const float mf_ = MREG;                                                     \
    int cur_; float accum_, carry_;                                             \
    {                                                                           \
      float Tz = fminf(fmaxf(fmaf(0.99f * supports[0], mf_, r_), -10.0f), 10.0f); \
      float b  = (Tz + 10.0f) * 2.5f;                                           \
      int   l  = (int)ceilf(b) - 1;  l = (l < 0) ? 0 : l;                       \
      float lf = (float)l;                                                      \
      cur_   = l;                                                               \
      accum_ = p[0] * (lf + 1.0f - b);                                          \
      carry_ = p[0] * (b - lf);                                                 \
    }                                                                           \
    _Pragma("unroll")                                                           \
    for (int j = 1; j < ATOMS; ++j) {                                           \
      float Tz = fminf(fmaxf(fmaf(0.99f * supports[j], mf_, r_), -10.0f), 10.0f); \
      float b  = (Tz + 10.0f) * 2.5f;                                           \
      int   l  = (int)ceilf(b) - 1;  l = (l < 0) ? 0 : l;                       \
      float lf = (float)l;                                                      \
      float wl = p[j] * (lf + 1.0f - b);                                        \
      float wu = p[j] * (b - lf);                                               \
      if (l != cur_) {                /* l advances by exactly 1 (step<1) */    \
        row[cur_] = accum_;                                                     \
        accum_ = carry_; carry_ = 0.0f; cur_ = l;                               \
      }                                                                         \
      accum_ += wl; carry_ += wu;                                               \
    }                                                                           \
    row[cur_]     = accum_;                                                     \
    row[cur_ + 1] = carry_;           /* cur_ <= 49 always */                   \
    /* writeout own tile: 816 float4 = 12 full rounds + 48-lane tail */         \
    float4* dst4 = (float4*)(out + (size_t)tt_ * TILE_F);                       \
    const float4* src4 = (const float4*)&smem[S][0];                            \
    _Pragma("unroll")                                                           \
    for (int k = 0; k < 12; ++k) dst4[lane + 64 * k] = src4[lane + 64 * k];     \
    if (lane < 48) dst4[lane + 768] = src4[lane + 768];                         \
    if (DO_ISSUE) {                                                             \
      WAIT_LGKM0();                   /* ds_reads done before DMA overwrites */ \
      SCHED_FENCE();                                                            \
      ISSUE_TILE(tt_ + 2, S, RREG, MREG);                                       \
    }                                                                           \
  } while (0)

__global__ __launch_bounds__(ROWS, 1) void c51_project(
    const float* __restrict__ reward,
    const float* __restrict__ dist,
    const float* __restrict__ supports,
    const int*   __restrict__ mask,
    float* __restrict__ out)
{
    __shared__ __align__(16) float smem[2][TILE_F];   // 26112 B -> 6 blocks/CU
    const int lane  = threadIdx.x;
    const int tile0 = blockIdx.x * TPB;

    float r0, m0, r1, m1;
    ISSUE_TILE(tile0 + 0, 0, r0, m0);
    ISSUE_TILE(tile0 + 1, 1, r1, m1);

    BODY(0, 0, r0, m0, true);
    BODY(1, 1, r1, m1, true);
    BODY(2, 0, r0, m0, false);
    BODY(3, 1, r1, m1, false);
}

extern "C" void kernel_launch(void* const* d_in, const int* in_sizes, int n_in,
                              void* d_out, int out_size, void* d_ws, size_t ws_size,
                              hipStream_t stream) {
    const float* reward   = (const float*)d_in[0];  // [B] f32
    const float* dist     = (const float*)d_in[1];  // [B, 51] f32
    const float* supports = (const float*)d_in[2];  // [51] f32
    const int*   mask     = (const int*)d_in[3];    // [B] i32
    float* out = (float*)d_out;                     // [B, 51] f32
    const int B     = in_sizes[0];                  // 1048576
    const int tiles = B / ROWS;                     // 16384
    const int grid  = tiles / TPB;                  // 4096
    c51_project<<<grid, ROWS, 0, stream>>>(reward, dist, supports, mask, out);
}